// Round 7
// baseline (290.019 us; speedup 1.0000x reference)
//
#include <hip/hip_runtime.h>

// DeepSeek MoE gate. Round 7: split-K=2, BM=128, m97-style 2-barrier K-loop
// with COUNTED vmcnt (no full drain in the main loop).
// - B (f16 hi/lo, fragment-major blob) staged via global_load_lds width=16
//   into double-buffered LDS (2x64 KB); barrier wait is vmcnt(4) so next-step
//   B DMA completes while A register loads stay in flight.
// - A (f32->f16 hi/lo) reg-staged into a single 32 KB LDS tile, written in a
//   short second barrier region (ds_write + lgkmcnt(0) only).
// - LDS = 160 KB exactly, 1 WG/CU, 8 waves (2 wr x 4 wc), grid 256.
// - Slice->XCD pinning: each XCD's blob half (3.67 MB) fits its 4 MB L2.
// - Partial f32 logits to ws; R3's proven epilogue kernel does
//   sum -> sigmoid+bias -> group-limited top-k.

#define TTOK 16384
#define EEXP 256
#define HDIM 7168
#define BM 128
#define BK 64
#define SPLITK 2
#define KSLICE (HDIM / SPLITK)  // 3584
#define NSTEP (KSLICE / BK)     // 56
#define NTHR 512
#define LDS_BYTES 163840        // B 2x65536 + A 32768
#define ABASE 131072
#define EPI_LDS (64 * 257 * 4)  // 65792

typedef __attribute__((ext_vector_type(4))) float f32x4;
typedef __attribute__((ext_vector_type(8))) _Float16 h8;

__device__ __forceinline__ void gload_lds16(const void* g, void* l) {
  typedef const __attribute__((address_space(1))) unsigned int gu32;
  typedef __attribute__((address_space(3))) unsigned int lu32;
  __builtin_amdgcn_global_load_lds((gu32*)g, (lu32*)l, 16, 0, 0);
}

// ---------------------------------------------------------------------------
// Kernel 1: W[256][7168] f32 -> fragment-major f16 hi/lo blob.
// Byte offset = (kcg*32 + eb*2 + hl)*1024 + lane*16; fragment [kcg][eb][hl]
// holds expert e = eb*16+(lane&15), k = kcg*32 + (lane>>4)*8 + j.
// ---------------------------------------------------------------------------
__global__ __launch_bounds__(64) void pack_w_kernel(const float* __restrict__ W,
                                                    _Float16* __restrict__ blob) {
  const int kcg = blockIdx.x;    // 0..223
  const int eb = blockIdx.y;     // 0..15
  const int lane = threadIdx.x;  // 0..63
  const int e = eb * 16 + (lane & 15);
  const int k0 = kcg * 32 + (lane >> 4) * 8;
  const float* src = W + (size_t)e * HDIM + k0;
  h8 hi, lo;
#pragma unroll
  for (int j = 0; j < 8; ++j) {
    float x = src[j];
    _Float16 h = (_Float16)x;
    hi[j] = h;
    lo[j] = (_Float16)((x - (float)h) * 2048.0f);  // exact residual, out of denormals
  }
  char* dst = (char*)blob + ((size_t)kcg * 32 + eb * 2) * 1024 + lane * 16;
  *(h8*)dst = hi;
  *(h8*)(dst + 1024) = lo;
}

// ---------------------------------------------------------------------------
// Kernel 2: split-K GEMM. One WG = 128 tokens x 256 experts x 3584 K.
// ---------------------------------------------------------------------------
__global__ __launch_bounds__(NTHR, 2) void gate_kernel(
    const float* __restrict__ X, const _Float16* __restrict__ Wblob,
    float* __restrict__ part) {
  extern __shared__ char smem[];

  const int bid = blockIdx.x;
  const int xcd = bid & 7;
  const int slice = xcd >> 2;                    // 0..1 (XCDs 0-3 / 4-7)
  const int tb = ((bid >> 3) << 2) | (bid & 3);  // 0..127
  const int tok0 = tb * BM;
  const int kbase = slice * KSLICE;
  const char* blobs = (const char*)Wblob + (size_t)slice * (KSLICE / 32) * 32768;

  const int tid = threadIdx.x;
  const int lane = tid & 63;
  const int wid = tid >> 6;
  const int wr = wid >> 2;  // 0..1 : 64-token stripe
  const int wc = wid & 3;   // 0..3 : 64-expert stripe

  f32x4 ra[4];  // A prefetch: 16 f32 = one row-quarter

  f32x4 acc1[4][4], acc2[4][4];
#pragma unroll
  for (int m = 0; m < 4; ++m)
#pragma unroll
    for (int n = 0; n < 4; ++n) {
      acc1[m][n] = (f32x4){0.f, 0.f, 0.f, 0.f};
      acc2[m][n] = (f32x4){0.f, 0.f, 0.f, 0.f};
    }

  auto LOADA = [&](int T) {
    const float* p = X + (size_t)(tok0 + (tid >> 2)) * HDIM + kbase + T * BK +
                     (tid & 3) * 16;
#pragma unroll
    for (int i = 0; i < 4; ++i) ra[i] = *(const f32x4*)(p + i * 4);
  };

  auto STAGEB = [&](int T, int buf) {
    const char* gs = blobs + (size_t)T * 65536 + lane * 16;
    char* lb = smem + buf * 65536;
#pragma unroll
    for (int i = 0; i < 8; ++i) {
      const int gb = i * 8 + wid;  // 0..63, 1 KB granules
      gload_lds16(gs + gb * 1024, lb + gb * 1024);
    }
  };

  auto STOREA = [&]() {
    const int row = tid >> 2, q = tid & 3;
    char* abh = smem + ABASE;
    char* abl = smem + ABASE + 16384;
#pragma unroll
    for (int c = 0; c < 2; ++c) {  // 2 h8 chunks from ra[2c], ra[2c+1]
      h8 hi, lo;
#pragma unroll
      for (int half = 0; half < 2; ++half) {
        const f32x4 v = (half == 0) ? ra[2 * c] : ra[2 * c + 1];
#pragma unroll
        for (int j = 0; j < 4; ++j) {
          const float x = v[j];
          const _Float16 h = (_Float16)x;
          hi[half * 4 + j] = h;
          lo[half * 4 + j] = (_Float16)((x - (float)h) * 2048.0f);
        }
      }
      const int cc = q * 2 + c;  // chunk col 0..7
      const int ix = row * 128 + ((cc ^ (row & 7)) << 4);
      *(h8*)(abh + ix) = hi;
      *(h8*)(abl + ix) = lo;
    }
  };

#define PHASE(S, BUF)                                                           \
  {                                                                             \
    const char* abh = smem + ABASE;                                             \
    const char* abl = smem + ABASE + 16384;                                     \
    const char* bb = smem + (BUF) * 65536;                                      \
    h8 ah[4], al[4];                                                            \
    _Pragma("unroll") for (int m = 0; m < 4; ++m) {                             \
      const int r_ = wr * 64 + m * 16 + (lane & 15);                            \
      const int c_ = ((S) * 4 + (lane >> 4)) ^ (r_ & 7);                        \
      const int ao_ = r_ * 128 + (c_ << 4);                                     \
      ah[m] = *(const h8*)(abh + ao_);                                          \
      al[m] = *(const h8*)(abl + ao_);                                          \
    }                                                                           \
    h8 bh[4], bl[4];                                                            \
    _Pragma("unroll") for (int n = 0; n < 4; ++n) {                             \
      const int bo_ = (((S) * 16 + (wc * 4 + n)) * 2) * 1024 + lane * 16;       \
      bh[n] = *(const h8*)(bb + bo_);                                           \
      bl[n] = *(const h8*)(bb + bo_ + 1024);                                    \
    }                                                                           \
    __builtin_amdgcn_s_setprio(1);                                              \
    _Pragma("unroll") for (int n = 0; n < 4; ++n)                               \
        _Pragma("unroll") for (int m = 0; m < 4; ++m) {                         \
      acc1[m][n] = __builtin_amdgcn_mfma_f32_16x16x32_f16(ah[m], bh[n], acc1[m][n], 0, 0, 0); \
      acc2[m][n] = __builtin_amdgcn_mfma_f32_16x16x32_f16(ah[m], bl[n], acc2[m][n], 0, 0, 0); \
      acc2[m][n] = __builtin_amdgcn_mfma_f32_16x16x32_f16(al[m], bh[n], acc2[m][n], 0, 0, 0); \
    }                                                                           \
    __builtin_amdgcn_s_setprio(0);                                              \
  }

  // Prologue: A loads first (oldest in FIFO -> STOREA's auto-wait is vmcnt(8)).
  LOADA(0);
  asm volatile("" ::: "memory");
  STAGEB(0, 0);
  STOREA();
  asm volatile("s_waitcnt vmcnt(0) lgkmcnt(0)" ::: "memory");
  __builtin_amdgcn_s_barrier();

  int buf = 0;
#pragma unroll 1
  for (int T = 0; T < NSTEP; ++T) {
    const bool pf = (T + 1 < NSTEP);
    if (pf) {
      STAGEB(T + 1, buf ^ 1);        // 8 DMA, oldest
      asm volatile("" ::: "memory");  // keep A loads after B DMA in the FIFO
      LOADA(T + 1);                   // 4 register loads, newest
    }
    PHASE(0, buf);
    PHASE(1, buf);
    if (pf) asm volatile("s_waitcnt vmcnt(4)" ::: "memory");  // B(T+1) done, ra flying
    __builtin_amdgcn_s_barrier();  // readers of A(T), B(T,buf) done
    if (pf) {
      STOREA();  // compiler drains ra (issued a full phase ago)
      asm volatile("s_waitcnt lgkmcnt(0)" ::: "memory");
      __builtin_amdgcn_s_barrier();  // A(T+1) visible
    }
    buf ^= 1;
  }

  // Partial f32 logits: part[slice][token][expert].
  // C/D layout: col = lane&15, row = (lane>>4)*4 + reg.
  float* pbase = part + ((size_t)slice * TTOK + tok0) * EEXP;
#pragma unroll
  for (int m = 0; m < 4; ++m)
#pragma unroll
    for (int n = 0; n < 4; ++n) {
      const int e = wc * 64 + n * 16 + (lane & 15);
      const int t0 = wr * 64 + m * 16 + (lane >> 4) * 4;
#pragma unroll
      for (int r = 0; r < 4; ++r)
        pbase[(size_t)(t0 + r) * EEXP + e] =
            acc1[m][n][r] + acc2[m][n][r] * (1.0f / 2048.0f);
    }
}

// ---------------------------------------------------------------------------
// Kernel 3: epilogue. 64 tokens/WG: sum 2 partials, sigmoid+bias -> LDS,
// then 64 lanes do per-token group-limited top-k. (Proven in R3.)
// ---------------------------------------------------------------------------
__global__ __launch_bounds__(256) void epilogue_kernel(
    const float* __restrict__ part, const float* __restrict__ bias,
    float* __restrict__ outw, float* __restrict__ outi) {
  extern __shared__ float sc[];  // [64][257]
  const int tid = threadIdx.x;
  const long t0 = (long)blockIdx.x * 64;

  const int e4 = (tid & 63) * 4;
  const int rsub = tid >> 6;
  const f32x4 bv = *(const f32x4*)(bias + e4);
#pragma unroll
  for (int rr = 0; rr < 16; ++rr) {
    const int row = rr * 4 + rsub;
    const f32x4 a = *(const f32x4*)(part + (t0 + row) * EEXP + e4);
    const f32x4 c = *(const f32x4*)(part + ((long)TTOK + t0 + row) * EEXP + e4);
#pragma unroll
    for (int j = 0; j < 4; ++j) {
      const float v = a[j] + c[j];
      sc[row * 257 + e4 + j] = 1.0f / (1.0f + expf(-v)) + bv[j];
    }
  }
  __syncthreads();

  if (tid < 64) {
    const float* s = sc + tid * 257;
    float gmax[8];
#pragma unroll
    for (int g = 0; g < 8; ++g) {
      float mx = -1e30f;
      for (int j = 0; j < 32; ++j) mx = fmaxf(mx, s[g * 32 + j]);
      gmax[g] = mx;
    }
    // top-4 groups (strict > keeps lowest index on ties, matching lax.top_k)
    unsigned selmask = 0;
    for (int it = 0; it < 4; ++it) {
      float best = -1e30f;
      int bi = 0;
      for (int g = 0; g < 8; ++g)
        if (!((selmask >> g) & 1) && gmax[g] > best) {
          best = gmax[g];
          bi = g;
        }
      selmask |= 1u << bi;
    }
    // stable top-8 over masked scores (masked-out groups contribute 0.0)
    float vals[8];
    int idx[8];
#pragma unroll
    for (int j = 0; j < 8; ++j) {
      vals[j] = -1e30f;
      idx[j] = 0;
    }
    for (int e = 0; e < 256; ++e) {
      const float v = ((selmask >> (e >> 5)) & 1) ? s[e] : 0.0f;
      if (v > vals[7]) {
        int p = 7;
        while (p > 0 && v > vals[p - 1]) {
          vals[p] = vals[p - 1];
          idx[p] = idx[p - 1];
          --p;
        }
        vals[p] = v;
        idx[p] = e;
      }
    }
    float ssum = 0.0f;
#pragma unroll
    for (int j = 0; j < 8; ++j) ssum += vals[j];
    const float den = ssum + 1e-6f;
    const long tg = t0 + tid;
#pragma unroll
    for (int j = 0; j < 8; ++j) {
      outw[tg * 8 + j] = vals[j] / den;
      outi[tg * 8 + j] = (float)idx[j];  // indices written as f32 values
    }
  }
}

extern "C" void kernel_launch(void* const* d_in, const int* in_sizes, int n_in,
                              void* d_out, int out_size, void* d_ws, size_t ws_size,
                              hipStream_t stream) {
  const float* X = (const float*)d_in[0];     // [16384,7168] f32
  const float* W = (const float*)d_in[1];     // [256,7168] f32
  const float* bias = (const float*)d_in[2];  // [256] f32

  _Float16* wblob = (_Float16*)d_ws;                       // 7.34 MB
  float* part = (float*)((char*)d_ws + (size_t)EEXP * HDIM * 4);  // 33.6 MB

  float* outw = (float*)d_out;            // [16384,8]
  float* outi = outw + (size_t)TTOK * 8;  // [16384,8] as f32 values

  hipFuncSetAttribute((const void*)gate_kernel,
                      hipFuncAttributeMaxDynamicSharedMemorySize, LDS_BYTES);
  hipFuncSetAttribute((const void*)epilogue_kernel,
                      hipFuncAttributeMaxDynamicSharedMemorySize, EPI_LDS);

  pack_w_kernel<<<dim3(HDIM / 32, EEXP / 16), 64, 0, stream>>>(W, wblob);
  gate_kernel<<<SPLITK * (TTOK / BM), NTHR, LDS_BYTES, stream>>>(X, wblob, part);
  epilogue_kernel<<<TTOK / 64, 256, EPI_LDS, stream>>>(part, bias, outw, outi);
}